// Round 8
// baseline (545.671 us; speedup 1.0000x reference)
//
#include <hip/hip_runtime.h>
#include <stdint.h>

// ---------------------------------------------------------------------------
// LogSparse attention (B=4, T=2048, E=512, H=8, head_dim=64, q/k width e=512)
//   0) convert x, w_qk to bf16; transpose+convert w_v, w_proj to [N][K] bf16
//   1) QK = x @ w_qk^T           (bf16 MFMA GEMM, C bf16 [8192][8192])
//   2) V  = x @ w_v + b_v        (bf16 MFMA GEMM, stored transposed [b,h,d,t])
//   3) memset O_f32/l partials; flash attention with kt-SPLIT jobs:
//      job = (bh, 128-row q-tile, 4-ktile slice) -> 2304 uniform jobs,
//      4 waves x 32 q-rows, K 4x8KB chunk buffers depth-3 counted-vmcnt,
//      no-max softmax (sums are kt-associative) -> atomicAdd partial O,l
//   4) normalize: ctx_bf = O/l
//   5) out = ctx @ w_proj + b_proj (f32 out)
// ---------------------------------------------------------------------------

typedef __attribute__((ext_vector_type(8))) short short8;
typedef __attribute__((ext_vector_type(4))) float f32x4;
typedef __attribute__((ext_vector_type(4))) unsigned short us4;

__device__ __forceinline__ f32x4 fzero4() { f32x4 z = {0.f, 0.f, 0.f, 0.f}; return z; }

__device__ __forceinline__ unsigned short f2bf(float f) {  // RNE f32->bf16
  unsigned u = __float_as_uint(f);
  u += 0x7fff + ((u >> 16) & 1);
  return (unsigned short)(u >> 16);
}

__device__ __forceinline__ void gload_lds16(const void* g, void* l) {
  __builtin_amdgcn_global_load_lds((const __attribute__((address_space(1))) void*)g,
                                   (__attribute__((address_space(3))) void*)l, 16, 0, 0);
}

// bijective XCD swizzle (nwg % 8 == 0 for all our grids)
__device__ __forceinline__ int xcd_swizzle(int flat, int nwg) {
  const int cpx = nwg >> 3;
  return (flat & 7) * cpx + (flat >> 3);
}

// ---------------------------------------------------------------------------
// GEMM: C[M,N] = A[M,K] * B[N,K]^T  (A,B bf16 row-major, K-contiguous)
// 128x128 tile, BK=32, 256 threads (4 waves, 2x2), 16x16x32 bf16 MFMA.
// EPI 0: C bf16 row-major, no bias
// EPI 1: V epilogue: bf16, +bias, stored transposed V_t[(b*512+col)][t]
// EPI 2: C f32 row-major, +bias
// ---------------------------------------------------------------------------
template <int EPI>
__global__ __launch_bounds__(256, 2) void gemm_bt(const unsigned short* __restrict__ A,
                                                  const unsigned short* __restrict__ B,
                                                  void* __restrict__ Cout,
                                                  const float* __restrict__ bias,
                                                  int M, int N, int K) {
  __shared__ unsigned short As[128 * 32];
  __shared__ unsigned short Bs[128 * 32];
  const int tid = threadIdx.x;
  const int wid = tid >> 6;
  const int lane = tid & 63;
  const int wm = wid >> 1, wn = wid & 1;
  const int nbx = (M + 127) / 128;
  const int sw = xcd_swizzle(blockIdx.y * gridDim.x + blockIdx.x, gridDim.x * gridDim.y);
  const long m0 = (long)(sw % nbx) * 128;
  const long n0 = (long)(sw / nbx) * 128;

  f32x4 acc[4][4];
#pragma unroll
  for (int i = 0; i < 4; ++i)
#pragma unroll
    for (int j = 0; j < 4; ++j) acc[i][j] = fzero4();

  const int lrow = tid >> 2;          // 0..63
  const int lcol = (tid & 3) * 8;     // 0,8,16,24
  const unsigned short* Ag = A + (m0 + lrow) * (long)K + lcol;
  const unsigned short* Bg = B + (n0 + lrow) * (long)K + lcol;
  unsigned short* Asl = As + tid * 8;
  unsigned short* Bsl = Bs + tid * 8;
  const long K64 = (long)64 * K;

  const int fr = lane & 15;
  const int fk = (lane >> 4) * 8;

  for (int k0 = 0; k0 < K; k0 += 32) {
    gload_lds16(Ag + k0, Asl);
    gload_lds16(Ag + K64 + k0, Asl + 2048);
    gload_lds16(Bg + k0, Bsl);
    gload_lds16(Bg + K64 + k0, Bsl + 2048);
    __syncthreads();
    short8 af[4], bfr[4];
#pragma unroll
    for (int i = 0; i < 4; ++i) af[i] = *(const short8*)&As[(wm * 64 + i * 16 + fr) * 32 + fk];
#pragma unroll
    for (int j = 0; j < 4; ++j) bfr[j] = *(const short8*)&Bs[(wn * 64 + j * 16 + fr) * 32 + fk];
#pragma unroll
    for (int i = 0; i < 4; ++i)
#pragma unroll
      for (int j = 0; j < 4; ++j)
        acc[i][j] = __builtin_amdgcn_mfma_f32_16x16x32_bf16(af[i], bfr[j], acc[i][j], 0, 0, 0);
    __syncthreads();
  }

  const int fg = lane >> 4;
#pragma unroll
  for (int i = 0; i < 4; ++i) {
#pragma unroll
    for (int j = 0; j < 4; ++j) {
      const long row0 = m0 + wm * 64 + i * 16 + fg * 4;  // +r
      const long col = n0 + wn * 64 + j * 16 + fr;
      if (EPI == 0) {
        unsigned short* C = (unsigned short*)Cout;
#pragma unroll
        for (int r = 0; r < 4; ++r) C[(row0 + r) * (long)N + col] = f2bf(acc[i][j][r]);
      } else if (EPI == 1) {
        unsigned short* C = (unsigned short*)Cout;
        const float bs = bias[col];
        const int b_ = (int)(row0 >> 11);
        const int t0 = (int)(row0 & 2047);
        us4 pk;
#pragma unroll
        for (int r = 0; r < 4; ++r) pk[r] = f2bf(acc[i][j][r] + bs);
        *(us4*)&C[((size_t)(b_ * 512 + col)) * 2048 + t0] = pk;  // [b,h,d][t]
      } else {
        float* C = (float*)Cout;
        const float bs = bias[col];
#pragma unroll
        for (int r = 0; r < 4; ++r) C[(row0 + r) * (long)N + col] = acc[i][j][r] + bs;
      }
    }
  }
}

// ---------------------------------------------------------------------------
// Flash attention, kt-split jobs. 2304 blocks, 256 threads (4 waves).
// job id -> (bh = id&31, r = 71-(id>>5) -> (q, slice)): q-tile = 128 rows
// (q in 0..15), slice = 4 key-tiles (last slice of even q = 2). Wave w owns
// rows q*128 + w*32 .. +31 (2 i-groups of 16). No-max softmax => O,l are
// kt-associative sums -> partials accumulated with atomicAdd into O_f32,l.
// K: 4 x 8KB chunk buffers [64 keys][64 e], XOR-swizzled (pre-swizzled global
// src), depth-3 counted-vmcnt (2 gloads/wave/chunk), 8 phases/ktile.
// ---------------------------------------------------------------------------
#define STAGE_CHUNK(BUF, GL)                                                  \
  do {                                                                        \
    const unsigned short* _src =                                              \
        Kg + (size_t)((GL) >> 3) * (64 * 8192) + ((GL) & 7) * 64;             \
    gload_lds16(_src, &Kb[BUF][tid * 8]);                                     \
    gload_lds16(_src + (size_t)32 * 8192, &Kb[BUF][2048 + tid * 8]);          \
  } while (0)

#define QK_COMPUTE(BUF, KS0)                                                  \
  __builtin_amdgcn_s_setprio(1);                                              \
  _Pragma("unroll") for (int e = 0; e < 2; ++e) {                             \
    _Pragma("unroll") for (int j = 0; j < 4; ++j) {                           \
      const short8 bfr = *(const short8*)&Kb[BUF][(j * 16 + fr) * 64 +        \
                                                  (((e * 4 + fg) ^ xsw) << 3)]; \
      s[0][j] = __builtin_amdgcn_mfma_f32_16x16x32_bf16(qreg[0][(KS0) + e],   \
                                                        bfr, s[0][j], 0, 0, 0); \
      s[1][j] = __builtin_amdgcn_mfma_f32_16x16x32_bf16(qreg[1][(KS0) + e],   \
                                                        bfr, s[1][j], 0, 0, 0); \
    }                                                                         \
  }                                                                           \
  __builtin_amdgcn_s_setprio(0);

// wait(N), barrier, stage local chunk P+3 (clamped dummy at tail), compute P
#define PHASE(N, P)                                                           \
  do {                                                                        \
    asm volatile("s_waitcnt vmcnt(" #N ")" ::: "memory");                     \
    asm volatile("s_barrier" ::: "memory");                                   \
    int _n3 = (kt - kt0) * 8 + (P) + 3;                                       \
    if (_n3 >= NC) _n3 = NC - 1;                                              \
    STAGE_CHUNK(((P) + 3) & 3, kt0 * 8 + _n3);                                \
    if (kt <= dkt) { QK_COMPUTE((P) & 3, (P) * 2); }                          \
  } while (0)

__global__ __launch_bounds__(256, 3) void flash_attn(const unsigned short* __restrict__ QK,
                                                     const unsigned short* __restrict__ Vt,
                                                     float* __restrict__ Opart,
                                                     float* __restrict__ lpart) {
  __shared__ unsigned short Kb[4][64 * 64];    // 4 x 8 KB, shared by 4 waves
  __shared__ unsigned short Plds[4][32 * 64];  // 4 KB per wave

  const int tid = threadIdx.x, wid = tid >> 6, lane = tid & 63;
  const int fr = lane & 15, fg = lane >> 4;
  const int xsw = fr & 7;

  // ---- job decode: id -> (bh, q, slice)
  const int id = blockIdx.x;
  const int bh = id & 31;
  const int b = bh >> 3, h = bh & 7;
  const int r_ = 71 - (id >> 5);  // 0..71, largest q first
  const int q = (r_ >= 1) + (r_ >= 2) + (r_ >= 4) + (r_ >= 6) + (r_ >= 9) + (r_ >= 12) +
                (r_ >= 16) + (r_ >= 20) + (r_ >= 25) + (r_ >= 30) + (r_ >= 36) +
                (r_ >= 42) + (r_ >= 49) + (r_ >= 56) + (r_ >= 64);
  const int mq = q >> 1;
  const int sl = r_ - (q + mq * (mq - 1) + (q & 1) * mq);  // r - cumprev(q)
  const int kt0 = sl * 4;
  const int nkt = 2 * q + 2;
  const int kt1 = (kt0 + 4 < nkt) ? kt0 + 4 : nkt;
  const int NC = (kt1 - kt0) * 8;           // local chunk count
  const int dkt = 2 * q + (wid >> 1);       // this wave's diagonal key-tile

  // ---- Q fragments -> registers: 2 i-groups x 16 e-steps (128 VGPR)
  short8 qreg[2][16];
  {
    const unsigned short* qp =
        QK + (size_t)(b * 2048 + q * 128 + wid * 32 + fr) * 8192 + h * 512 + fg * 8;
#pragma unroll
    for (int i = 0; i < 2; ++i)
#pragma unroll
      for (int e = 0; e < 16; ++e)
        qreg[i][e] = *(const short8*)(qp + (size_t)i * 16 * 8192 + e * 32);
  }

  // ---- mask bitmaps (bit r*4+j) per i-group
  unsigned m_gen[2], m_t0[2], m_diag[2];
#pragma unroll
  for (int i = 0; i < 2; ++i) {
    const int lrow64 = (wid & 1) * 32 + i * 16 + fg * 4;  // row within 64-tile
    m_gen[i] = 0xFFFFu; m_t0[i] = 0xFFFFu; m_diag[i] = 0u;
    if (q <= 2) {  // global rows < 384: plain causal
#pragma unroll
      for (int r = 0; r < 4; ++r)
#pragma unroll
        for (int j = 0; j < 4; ++j)
          if (j * 16 + fr <= lrow64 + r) m_diag[i] |= 1u << (r * 4 + j);
    } else {
      m_gen[i] = 0; m_t0[i] = 0;
      const unsigned long long SBITS = 0x20002022FFull;  // t in {0..7,9,13,21,37}
#pragma unroll
      for (int r = 0; r < 4; ++r) {
        const int irow = q * 128 + wid * 32 + i * 16 + fg * 4 + r;
#pragma unroll
        for (int j = 0; j < 4; ++j) {
          const int c = j * 16 + fr;
          const int t = (irow - c) & 63;
          const unsigned g = (unsigned)((SBITS >> t) & 1ull);
          const unsigned bit = 1u << (r * 4 + j);
          if (g) m_gen[i] |= bit;
          if ((c + t >= 5) ? (g != 0) : (t >= 1)) m_t0[i] |= bit;  // terminal rule
          if (g && c <= lrow64 + r) m_diag[i] |= bit;
        }
      }
    }
  }

  f32x4 o[2][4], ol[2];
#pragma unroll
  for (int i = 0; i < 2; ++i) {
    ol[i] = fzero4();
#pragma unroll
    for (int j = 0; j < 4; ++j) o[i][j] = fzero4();
  }

  short8 ones;
#pragma unroll
  for (int z = 0; z < 8; ++z) ones[z] = (short)0x3F80;  // bf16 1.0

  // ---- K staging base (pre-swizzled global source; LDS dest linear)
  // chunk = [64 keys][64 e]: 256 threads x 2 x 16B; rows tid>>3 and +32
  const int srow = tid >> 3;                  // 0..31
  const int sslot = (tid & 7) ^ (srow & 7);   // inverse-swizzled 16B slot
  const unsigned short* Kg =
      QK + (size_t)(b * 2048 + srow) * 8192 + 4096 + h * 512 + sslot * 8;

  // prologue: local chunks 0,1,2 -> buffers 0,1,2 (depth-3)
  STAGE_CHUNK(0, kt0 * 8 + 0);
  STAGE_CHUNK(1, kt0 * 8 + 1);
  STAGE_CHUNK(2, kt0 * 8 + 2);

  for (int kt = kt0; kt < kt1; ++kt) {
    f32x4 s[2][4];
#pragma unroll
    for (int i = 0; i < 2; ++i)
#pragma unroll
      for (int j = 0; j < 4; ++j) s[i][j] = fzero4();
    short8 vreg[2][4];

    PHASE(4, 0);
    PHASE(4, 1);
    PHASE(4, 2);
    PHASE(4, 3);

    // ---- phase 4: V loads first (pinned before stage), then stage+compute
    asm volatile("s_waitcnt vmcnt(4)" ::: "memory");
    asm volatile("s_barrier" ::: "memory");
    if (kt <= dkt) {
#pragma unroll
      for (int ks = 0; ks < 2; ++ks)
#pragma unroll
        for (int jd = 0; jd < 4; ++jd)
          vreg[ks][jd] = *(const short8*)(Vt + (size_t)(bh * 64 + jd * 16 + fr) * 2048 +
                                          kt * 64 + ks * 32 + fg * 8);
    }
    __builtin_amdgcn_sched_barrier(0);  // keep V-issue before the stage below
    {
      int _n3 = (kt - kt0) * 8 + 7;
      if (_n3 >= NC) _n3 = NC - 1;
      STAGE_CHUNK(3, kt0 * 8 + _n3);
    }
    if (kt <= dkt) { QK_COMPUTE(0, 8); }

    PHASE(12, 5);
    PHASE(12, 6);
    PHASE(4, 7);

    if (kt <= dkt) {
      // ---- no-max softmax: P = exp2(s * scale * log2e), masked -> 0
#pragma unroll
      for (int i = 0; i < 2; ++i) {
        unsigned mm = (kt == 0) ? m_t0[i] : m_gen[i];
        if (kt == dkt) mm &= m_diag[i];
#pragma unroll
        for (int r = 0; r < 4; ++r) {
#pragma unroll
          for (int j = 0; j < 4; ++j) {
            float v = s[i][j][r] * 0.18033688f;  // 0.125 * log2(e)
            v = ((mm >> (r * 4 + j)) & 1u) ? v : -1e30f;
            const float p = __builtin_amdgcn_exp2f(v);
            Plds[wid][(i * 16 + fg * 4 + r) * 64 +
                      (((j * 2 + (fr >> 3)) ^ ((fg * 4 + r) & 7)) << 3) + (fr & 7)] =
                f2bf(p);
          }
        }
      }

      // ---- PV + row-sum (ones column)
      __builtin_amdgcn_s_setprio(1);
#pragma unroll
      for (int i = 0; i < 2; ++i) {
#pragma unroll
        for (int ks = 0; ks < 2; ++ks) {
          const short8 pa = *(const short8*)&Plds[wid][(i * 16 + fr) * 64 +
                                                       (((ks * 4 + fg) ^ xsw) << 3)];
#pragma unroll
          for (int jd = 0; jd < 4; ++jd)
            o[i][jd] =
                __builtin_amdgcn_mfma_f32_16x16x32_bf16(pa, vreg[ks][jd], o[i][jd], 0, 0, 0);
          ol[i] = __builtin_amdgcn_mfma_f32_16x16x32_bf16(pa, ones, ol[i], 0, 0, 0);
        }
      }
      __builtin_amdgcn_s_setprio(0);
    }
  }

  asm volatile("s_waitcnt vmcnt(0)" ::: "memory");  // drain dangling dummy stages

  // ---- epilogue: atomic partial accumulation
#pragma unroll
  for (int i = 0; i < 2; ++i) {
    const int trow = q * 128 + wid * 32 + i * 16 + fg * 4;  // +r
#pragma unroll
    for (int r = 0; r < 4; ++r) {
      float* op = Opart + ((size_t)bh * 2048 + trow + r) * 64;
#pragma unroll
      for (int jd = 0; jd < 4; ++jd) atomicAdd(op + jd * 16 + fr, o[i][jd][r]);
      if (fr == 0) atomicAdd(lpart + (size_t)bh * 2048 + trow + r, ol[i][r]);
    }
  }
}

// ---------------------------------------------------------------------------
// normalize: ctx_bf[b*2048+t][h*64+d] = bf16(O[bh][t][d] / l[bh][t])
// ---------------------------------------------------------------------------
__global__ void normalize_k(const float* __restrict__ O, const float* __restrict__ l,
                            unsigned short* __restrict__ ctx) {
  const int i = blockIdx.x * 256 + threadIdx.x;  // over 1,048,576 float4 groups
  const int row = i >> 4;                        // bh*2048 + t
  const int g = i & 15;                          // d-group (4 d's)
  const float4 ov = ((const float4*)O)[i];
  const float inv = 1.0f / l[row];
  const int b = row >> 14, h = (row >> 11) & 7, t = row & 2047;
  us4 pk;
  pk[0] = f2bf(ov.x * inv);
  pk[1] = f2bf(ov.y * inv);
  pk[2] = f2bf(ov.z * inv);
  pk[3] = f2bf(ov.w * inv);
  *(us4*)&ctx[((size_t)(b * 2048 + t)) * 512 + h * 64 + g * 4] = pk;
}

// ---------------------------------------------------------------------------
// Conversions
// ---------------------------------------------------------------------------
__global__ void f32_to_bf16_k(const float* __restrict__ in, unsigned short* __restrict__ out,
                              int n4) {
  const int i = blockIdx.x * 256 + threadIdx.x;
  if (i < n4) {
    const float4 v = ((const float4*)in)[i];
    us4 o;
    o[0] = f2bf(v.x);
    o[1] = f2bf(v.y);
    o[2] = f2bf(v.z);
    o[3] = f2bf(v.w);
    ((us4*)out)[i] = o;
  }
}

// out[n][k] = bf16(in[k][n]) for 512x512 weight (x @ W -> C = A * W^T form)
__global__ void transpose_w_k(const float* __restrict__ in, unsigned short* __restrict__ out) {
  const int idx = blockIdx.x * 256 + threadIdx.x;
  const int row = idx >> 9, col = idx & 511;
  out[idx] = f2bf(in[col * 512 + row]);
}

// ---------------------------------------------------------------------------
extern "C" void kernel_launch(void* const* d_in, const int* in_sizes, int n_in,
                              void* d_out, int out_size, void* d_ws, size_t ws_size,
                              hipStream_t stream) {
  (void)in_sizes; (void)n_in; (void)out_size; (void)ws_size;
  const float* x = (const float*)d_in[0];
  const float* wqk = (const float*)d_in[1];
  const float* wv = (const float*)d_in[2];
  const float* bv = (const float*)d_in[3];
  const float* wp = (const float*)d_in[4];
  const float* bp = (const float*)d_in[5];
  // d_in[6] (mask) unused: mask computed analytically in-kernel.

  char* ws = (char*)d_ws;
  // Phase A (converts + GEMMs): x_bf [0,8M), wqk_bf [8M,16M), wv_t [16M,16.5M)
  // Phase B (flash + normalize): O_f32 [0,16M), l [16M,16.25M)  <- memset after GEMMs
  unsigned short* x_bf   = (unsigned short*)(ws + 0);                    //   8 MB [8192][512]
  unsigned short* wqk_bf = (unsigned short*)(ws + (size_t)8 * 1048576);  //   8 MB [8192][512]
  unsigned short* wv_t   = (unsigned short*)(ws + (size_t)16 * 1048576); // 0.5 MB [512][512]
  unsigned short* wp_t   = (unsigned short*)(ws + (size_t)17 * 1048576); // 0.5 MB [512][512]
  unsigned short* qk_bf  = (unsigned short*)(ws + (size_t)18 * 1048576); // 128 MB [8192][8192]
  unsigned short* v_t    = (unsigned short*)(ws + (size_t)146 * 1048576);//   8 MB [2048][2048]
  unsigned short* ctx_bf = (unsigned short*)(ws + (size_t)154 * 1048576);//   8 MB [8192][512]
  float* O_f32 = (float*)(ws + 0);                                       //  16 MB partial O
  float* lsum  = (float*)(ws + (size_t)16 * 1048576);                    // 256 KB partial l

  f32_to_bf16_k<<<4096, 256, 0, stream>>>(x, x_bf, 1048576);
  f32_to_bf16_k<<<4096, 256, 0, stream>>>(wqk, wqk_bf, 1048576);
  transpose_w_k<<<1024, 256, 0, stream>>>(wv, wv_t);
  transpose_w_k<<<1024, 256, 0, stream>>>(wp, wp_t);

  // QK = x @ w_qk^T : [8192][8192] bf16 (cols 0..4095 = Q, 4096..8191 = K)
  gemm_bt<0><<<dim3(64, 64), 256, 0, stream>>>(x_bf, wqk_bf, qk_bf, nullptr, 8192, 8192, 512);
  // V = x @ w_v + b_v, stored transposed [ (b*8+h)*64+d ][ t ]
  gemm_bt<1><<<dim3(64, 4), 256, 0, stream>>>(x_bf, wv_t, v_t, bv, 8192, 512, 512);

  // zero the partial buffers (x_bf/wqk_bf/wv_t are dead now)
  hipMemsetAsync(ws, 0, (size_t)16 * 1048576 + 262144, stream);

  flash_attn<<<2304, 256, 0, stream>>>(qk_bf, v_t, O_f32, lsum);

  normalize_k<<<4096, 256, 0, stream>>>(O_f32, lsum, ctx_bf);

  // out = ctx @ w_proj + b_proj (f32)
  gemm_bt<2><<<dim3(64, 4), 256, 0, stream>>>(ctx_bf, wp_t, d_out, bp, 8192, 512, 512);
}

// Round 9
// 286.311 us; speedup vs baseline: 1.9059x; 1.9059x over previous
//
#include <hip/hip_runtime.h>
#include <stdint.h>

// ---------------------------------------------------------------------------
// LogSparse attention (B=4, T=2048, E=512, H=8, head_dim=64, q/k width e=512)
//   0) convert x, w_qk to bf16; transpose+convert w_v, w_proj to [N][K] bf16
//   1) QK = x @ w_qk^T           (bf16 MFMA GEMM, C bf16 [8192][8192])
//   2) V  = x @ w_v + b_v        (bf16 MFMA GEMM, stored transposed [b,h,d,t])
//   3) flash attention -> ctx bf16: 512 UNIFORM blocks (paired q-tiles
//      31-p and p = 33 ktiles each), 4 waves split 2x2 (32 rows x 32 keys),
//      K dbuf chunks [64k x 256e] + syncthreads, no-max softmax,
//      per-wave partial O/l summed once per tile via LDS.
//   4) out = ctx @ w_proj + b_proj (f32 out)
// ---------------------------------------------------------------------------

typedef __attribute__((ext_vector_type(8))) short short8;
typedef __attribute__((ext_vector_type(4))) float f32x4;
typedef __attribute__((ext_vector_type(4))) unsigned short us4;

__device__ __forceinline__ f32x4 fzero4() { f32x4 z = {0.f, 0.f, 0.f, 0.f}; return z; }

__device__ __forceinline__ unsigned short f2bf(float f) {  // RNE f32->bf16
  unsigned u = __float_as_uint(f);
  u += 0x7fff + ((u >> 16) & 1);
  return (unsigned short)(u >> 16);
}

__device__ __forceinline__ void gload_lds16(const void* g, void* l) {
  __builtin_amdgcn_global_load_lds((const __attribute__((address_space(1))) void*)g,
                                   (__attribute__((address_space(3))) void*)l, 16, 0, 0);
}

// bijective XCD swizzle (nwg % 8 == 0 for all our grids)
__device__ __forceinline__ int xcd_swizzle(int flat, int nwg) {
  const int cpx = nwg >> 3;
  return (flat & 7) * cpx + (flat >> 3);
}

// ---------------------------------------------------------------------------
// GEMM: C[M,N] = A[M,K] * B[N,K]^T  (A,B bf16 row-major, K-contiguous)
// 128x128 tile, BK=32, 256 threads (4 waves, 2x2), 16x16x32 bf16 MFMA.
// EPI 0: C bf16 row-major, no bias
// EPI 1: V epilogue: bf16, +bias, stored transposed V_t[(b*512+col)][t]
// EPI 2: C f32 row-major, +bias
// ---------------------------------------------------------------------------
template <int EPI>
__global__ __launch_bounds__(256, 2) void gemm_bt(const unsigned short* __restrict__ A,
                                                  const unsigned short* __restrict__ B,
                                                  void* __restrict__ Cout,
                                                  const float* __restrict__ bias,
                                                  int M, int N, int K) {
  __shared__ unsigned short As[128 * 32];
  __shared__ unsigned short Bs[128 * 32];
  const int tid = threadIdx.x;
  const int wid = tid >> 6;
  const int lane = tid & 63;
  const int wm = wid >> 1, wn = wid & 1;
  const int nbx = (M + 127) / 128;
  const int sw = xcd_swizzle(blockIdx.y * gridDim.x + blockIdx.x, gridDim.x * gridDim.y);
  const long m0 = (long)(sw % nbx) * 128;
  const long n0 = (long)(sw / nbx) * 128;

  f32x4 acc[4][4];
#pragma unroll
  for (int i = 0; i < 4; ++i)
#pragma unroll
    for (int j = 0; j < 4; ++j) acc[i][j] = fzero4();

  const int lrow = tid >> 2;          // 0..63
  const int lcol = (tid & 3) * 8;     // 0,8,16,24
  const unsigned short* Ag = A + (m0 + lrow) * (long)K + lcol;
  const unsigned short* Bg = B + (n0 + lrow) * (long)K + lcol;
  unsigned short* Asl = As + tid * 8;
  unsigned short* Bsl = Bs + tid * 8;
  const long K64 = (long)64 * K;

  const int fr = lane & 15;
  const int fk = (lane >> 4) * 8;

  for (int k0 = 0; k0 < K; k0 += 32) {
    gload_lds16(Ag + k0, Asl);
    gload_lds16(Ag + K64 + k0, Asl + 2048);
    gload_lds16(Bg + k0, Bsl);
    gload_lds16(Bg + K64 + k0, Bsl + 2048);
    __syncthreads();
    short8 af[4], bfr[4];
#pragma unroll
    for (int i = 0; i < 4; ++i) af[i] = *(const short8*)&As[(wm * 64 + i * 16 + fr) * 32 + fk];
#pragma unroll
    for (int j = 0; j < 4; ++j) bfr[j] = *(const short8*)&Bs[(wn * 64 + j * 16 + fr) * 32 + fk];
#pragma unroll
    for (int i = 0; i < 4; ++i)
#pragma unroll
      for (int j = 0; j < 4; ++j)
        acc[i][j] = __builtin_amdgcn_mfma_f32_16x16x32_bf16(af[i], bfr[j], acc[i][j], 0, 0, 0);
    __syncthreads();
  }

  const int fg = lane >> 4;
#pragma unroll
  for (int i = 0; i < 4; ++i) {
#pragma unroll
    for (int j = 0; j < 4; ++j) {
      const long row0 = m0 + wm * 64 + i * 16 + fg * 4;  // +r
      const long col = n0 + wn * 64 + j * 16 + fr;
      if (EPI == 0) {
        unsigned short* C = (unsigned short*)Cout;
#pragma unroll
        for (int r = 0; r < 4; ++r) C[(row0 + r) * (long)N + col] = f2bf(acc[i][j][r]);
      } else if (EPI == 1) {
        unsigned short* C = (unsigned short*)Cout;
        const float bs = bias[col];
        const int b_ = (int)(row0 >> 11);
        const int t0 = (int)(row0 & 2047);
        us4 pk;
#pragma unroll
        for (int r = 0; r < 4; ++r) pk[r] = f2bf(acc[i][j][r] + bs);
        *(us4*)&C[((size_t)(b_ * 512 + col)) * 2048 + t0] = pk;  // [b,h,d][t]
      } else {
        float* C = (float*)Cout;
        const float bs = bias[col];
#pragma unroll
        for (int r = 0; r < 4; ++r) C[(row0 + r) * (long)N + col] = acc[i][j][r] + bs;
      }
    }
  }
}

// ---------------------------------------------------------------------------
// Flash attention. 512 uniform blocks, 256 threads (4 waves, 2x2 split).
// Block id -> xcd = id&7, bh = xcd*4 + ((id>>3)&3), p = id>>5.
// Processes q-tiles (31-p) then (p): 33 ktiles total per block (uniform).
// Wave (wm,wn): q-rows wm*32..+31 (2 i-groups), keys wn*32..+31 (2 j).
// K: double-buffered [64 keys][256 e] chunks (2 per ktile), XOR-swizzled
// via pre-swizzled global source. V: global->reg. P: wave-private LDS.
// No-max softmax (key-associative) -> per-wave partial O,l; one LDS
// combine per tile. Zero atomics, zero Q refetch.
// ---------------------------------------------------------------------------
#define STAGE(BUF, G)                                                          \
  do {                                                                         \
    const int _kt = (G) >> 1, _hf = (G) & 1;                                   \
    const unsigned short* _src = Kg + (size_t)(_kt) * (64 * 8192) + _hf * 256; \
    _Pragma("unroll") for (int _r = 0; _r < 8; ++_r)                           \
        gload_lds16(_src + (size_t)_r * 8 * 8192, &Kb[BUF][_r * 2048 + tid * 8]); \
  } while (0)

#define QK_HALF(BUF, HF)                                                       \
  __builtin_amdgcn_s_setprio(1);                                               \
  _Pragma("unroll") for (int e8 = 0; e8 < 8; ++e8) {                           \
    _Pragma("unroll") for (int j = 0; j < 2; ++j) {                            \
      const int _row = wn * 32 + j * 16 + fr;                                  \
      const short8 bfr = *(const short8*)&Kb[BUF][_row * 256 +                 \
                                                  (((e8 * 4 + fg) ^ xsw) << 3)]; \
      s[0][j] = __builtin_amdgcn_mfma_f32_16x16x32_bf16(qreg[0][(HF)*8 + e8],  \
                                                        bfr, s[0][j], 0, 0, 0); \
      s[1][j] = __builtin_amdgcn_mfma_f32_16x16x32_bf16(qreg[1][(HF)*8 + e8],  \
                                                        bfr, s[1][j], 0, 0, 0); \
    }                                                                          \
  }                                                                            \
  __builtin_amdgcn_s_setprio(0);

__global__ __launch_bounds__(256, 2) void flash_attn(const unsigned short* __restrict__ QK,
                                                     const unsigned short* __restrict__ Vt,
                                                     unsigned short* __restrict__ ctx) {
  __shared__ unsigned short Kb[2][64 * 256];   // 2 x 32 KB (dbuf K chunks)
  __shared__ unsigned short Plds[4][32 * 32];  // 2 KB per wave

  const int tid = threadIdx.x, wid = tid >> 6, lane = tid & 63;
  const int fr = lane & 15, fg = lane >> 4;
  const int xsw = fr & 7;
  const int wm = wid >> 1, wn = wid & 1;

  const int id = blockIdx.x;
  const int bh = (id & 7) * 4 + ((id >> 3) & 3);  // 4 bh per XCD (K L2 locality)
  const int p = id >> 5;                          // 0..15
  const int b = bh >> 3, h = bh & 7;

  // K staging base (pre-swizzled global source; LDS dest linear).
  // round r: keys r*8 + (tid>>5); 16B slot (tid&31) holds global slot ^ key&7
  const int gslot = (tid & 31) ^ (tid >> 5);
  const unsigned short* Kg =
      QK + (size_t)(b * 2048 + (tid >> 5)) * 8192 + 4096 + h * 512 + gslot * 8;

  short8 ones;
#pragma unroll
  for (int z = 0; z < 8; ++z) ones[z] = (short)0x3F80;  // bf16 1.0

  float* Osc = (float*)&Kb[0][0];    // combine scratch (16 KB), reused
  float* lsc = (float*)&Kb[1][0];    // 256 B

  for (int tile = 0; tile < 2; ++tile) {
    const int qt = (tile == 0) ? (31 - p) : p;

    // ---- Q fragments: rows qt*64 + wm*32 + {i*16} + fr, 16 e-steps (128 VGPR)
    short8 qreg[2][16];
    {
      const unsigned short* qp =
          QK + (size_t)(b * 2048 + qt * 64 + wm * 32 + fr) * 8192 + h * 512 + fg * 8;
#pragma unroll
      for (int i = 0; i < 2; ++i)
#pragma unroll
        for (int e = 0; e < 16; ++e)
          qreg[i][e] = *(const short8*)(qp + (size_t)i * 16 * 8192 + e * 32);
    }

    // ---- mask bitmaps, bit r*2+j (8 bits), cols c = wn*32 + j*16 + fr
    unsigned m_gen[2], m_t0[2], m_diag[2];
#pragma unroll
    for (int i = 0; i < 2; ++i) {
      const int lrow = wm * 32 + i * 16 + fg * 4;  // row within 64-row tile
      m_gen[i] = 0xFFu; m_t0[i] = 0xFFu; m_diag[i] = 0u;
      if (qt <= 5) {  // global rows < 384: plain causal
#pragma unroll
        for (int r = 0; r < 4; ++r)
#pragma unroll
          for (int j = 0; j < 2; ++j)
            if (wn * 32 + j * 16 + fr <= lrow + r) m_diag[i] |= 1u << (r * 2 + j);
      } else {
        m_gen[i] = 0; m_t0[i] = 0;
        const unsigned long long SBITS = 0x20002022FFull;  // t in {0..7,9,13,21,37}
#pragma unroll
        for (int r = 0; r < 4; ++r) {
          const int irow = qt * 64 + lrow + r;
#pragma unroll
          for (int j = 0; j < 2; ++j) {
            const int c = wn * 32 + j * 16 + fr;
            const int t = (irow - c) & 63;
            const unsigned g = (unsigned)((SBITS >> t) & 1ull);
            const unsigned bit = 1u << (r * 2 + j);
            if (g) m_gen[i] |= bit;
            if ((c + t >= 5) ? (g != 0) : (t >= 1)) m_t0[i] |= bit;  // terminal rule
            if (g && c <= lrow + r) m_diag[i] |= bit;
          }
        }
      }
    }

    f32x4 o[2][4], ol[2];
#pragma unroll
    for (int i = 0; i < 2; ++i) {
      ol[i] = fzero4();
#pragma unroll
      for (int j = 0; j < 4; ++j) o[i][j] = fzero4();
    }

    STAGE(0, 0);  // prologue: chunk 0 -> buf 0

    for (int kt = 0; kt <= qt; ++kt) {
      f32x4 s[2][2];
#pragma unroll
      for (int i = 0; i < 2; ++i)
#pragma unroll
        for (int j = 0; j < 2; ++j) s[i][j] = fzero4();

      // half 0: compute buf0, stage buf1 (chunk kt*2+1, always exists)
      __syncthreads();
      STAGE(1, kt * 2 + 1);
      QK_HALF(0, 0);

      // half 1: compute buf1, stage buf0 (chunk (kt+1)*2) unless last ktile
      __syncthreads();
      if (kt < qt) STAGE(0, (kt + 1) * 2);
      // V fragments for this wave's 32 keys (global->reg, L2-resident)
      short8 vreg[4];
#pragma unroll
      for (int jd = 0; jd < 4; ++jd)
        vreg[jd] = *(const short8*)(Vt + (size_t)(bh * 64 + jd * 16 + fr) * 2048 +
                                    kt * 64 + wn * 32 + fg * 8);
      QK_HALF(1, 1);

      // ---- no-max softmax: P = exp2(s * scale * log2e), masked -> 0
#pragma unroll
      for (int i = 0; i < 2; ++i) {
        unsigned mm = (kt == 0) ? m_t0[i] : m_gen[i];
        if (kt == qt) mm &= m_diag[i];
#pragma unroll
        for (int r = 0; r < 4; ++r) {
#pragma unroll
          for (int j = 0; j < 2; ++j) {
            float v = s[i][j][r] * 0.18033688f;  // 0.125 * log2(e)
            v = ((mm >> (r * 2 + j)) & 1u) ? v : -1e30f;
            const float pv = __builtin_amdgcn_exp2f(v);
            const int prow = i * 16 + fg * 4 + r;  // prow & 3 == r
            Plds[wid][prow * 32 + ((((j << 1) + (fr >> 3)) ^ r) << 3) + (fr & 7)] =
                f2bf(pv);
          }
        }
      }

      // ---- PV + row-sum (ones column): K=32, one MFMA step per (i,jd)
      __builtin_amdgcn_s_setprio(1);
#pragma unroll
      for (int i = 0; i < 2; ++i) {
        const int arow = i * 16 + fr;
        const short8 pa = *(const short8*)&Plds[wid][arow * 32 + ((fg ^ (fr & 3)) << 3)];
#pragma unroll
        for (int jd = 0; jd < 4; ++jd)
          o[i][jd] = __builtin_amdgcn_mfma_f32_16x16x32_bf16(pa, vreg[jd], o[i][jd], 0, 0, 0);
        ol[i] = __builtin_amdgcn_mfma_f32_16x16x32_bf16(pa, ones, ol[i], 0, 0, 0);
      }
      __builtin_amdgcn_s_setprio(0);
    }

    // ---- combine wn=0 + wn=1 partials via LDS; normalize; write ctx
    __syncthreads();  // all staging drained (vmcnt), Kb free for scratch
    if (wn == 1) {
#pragma unroll
      for (int i = 0; i < 2; ++i) {
#pragma unroll
        for (int r = 0; r < 4; ++r) {
          const int row32 = wm * 32 + i * 16 + fg * 4 + r;
#pragma unroll
          for (int jd = 0; jd < 4; ++jd)
            Osc[row32 * 64 + jd * 16 + fr] = o[i][jd][r];
          if (fr == 0) lsc[row32] = ol[i][r];
        }
      }
    }
    __syncthreads();
    if (wn == 0) {
#pragma unroll
      for (int i = 0; i < 2; ++i) {
#pragma unroll
        for (int r = 0; r < 4; ++r) {
          const int row32 = wm * 32 + i * 16 + fg * 4 + r;
          const float l = ol[i][r] + lsc[row32];
          const float inv = 1.0f / l;
          unsigned short* cp =
              ctx + (size_t)(b * 2048 + qt * 64 + row32) * 512 + h * 64;
#pragma unroll
          for (int jd = 0; jd < 4; ++jd) {
            const float v = o[i][jd][r] + Osc[row32 * 64 + jd * 16 + fr];
            cp[jd * 16 + fr] = f2bf(v * inv);
          }
        }
      }
    }
    __syncthreads();  // scratch reads done before next tile's staging
  }
}

// ---------------------------------------------------------------------------
// Conversions
// ---------------------------------------------------------------------------
__global__ void f32_to_bf16_k(const float* __restrict__ in, unsigned short* __restrict__ out,
                              int n4) {
  const int i = blockIdx.x * 256 + threadIdx.x;
  if (i < n4) {
    const float4 v = ((const float4*)in)[i];
    us4 o;
    o[0] = f2bf(v.x);
    o[1] = f2bf(v.y);
    o[2] = f2bf(v.z);
    o[3] = f2bf(v.w);
    ((us4*)out)[i] = o;
  }
}

// out[n][k] = bf16(in[k][n]) for 512x512 weight (x @ W -> C = A * W^T form)
__global__ void transpose_w_k(const float* __restrict__ in, unsigned short* __restrict__ out) {
  const int idx = blockIdx.x * 256 + threadIdx.x;
  const int row = idx >> 9, col = idx & 511;
  out[idx] = f2bf(in[col * 512 + row]);
}

// ---------------------------------------------------------------------------
extern "C" void kernel_launch(void* const* d_in, const int* in_sizes, int n_in,
                              void* d_out, int out_size, void* d_ws, size_t ws_size,
                              hipStream_t stream) {
  (void)in_sizes; (void)n_in; (void)out_size; (void)ws_size;
  const float* x = (const float*)d_in[0];
  const float* wqk = (const float*)d_in[1];
  const float* wv = (const float*)d_in[2];
  const float* bv = (const float*)d_in[3];
  const float* wp = (const float*)d_in[4];
  const float* bp = (const float*)d_in[5];
  // d_in[6] (mask) unused: mask computed analytically in-kernel.

  char* ws = (char*)d_ws;
  unsigned short* x_bf   = (unsigned short*)(ws + 0);                    //   8 MB [8192][512]
  unsigned short* wqk_bf = (unsigned short*)(ws + (size_t)8 * 1048576);  //   8 MB [8192][512]
  unsigned short* wv_t   = (unsigned short*)(ws + (size_t)16 * 1048576); // 0.5 MB [512][512]
  unsigned short* wp_t   = (unsigned short*)(ws + (size_t)17 * 1048576); // 0.5 MB [512][512]
  unsigned short* qk_bf  = (unsigned short*)(ws + (size_t)18 * 1048576); // 128 MB [8192][8192]
  unsigned short* v_t    = (unsigned short*)(ws + (size_t)146 * 1048576);//   8 MB [2048][2048]
  unsigned short* ctx_bf = (unsigned short*)(ws + (size_t)154 * 1048576);//   8 MB [8192][512]

  f32_to_bf16_k<<<4096, 256, 0, stream>>>(x, x_bf, 1048576);
  f32_to_bf16_k<<<4096, 256, 0, stream>>>(wqk, wqk_bf, 1048576);
  transpose_w_k<<<1024, 256, 0, stream>>>(wv, wv_t);
  transpose_w_k<<<1024, 256, 0, stream>>>(wp, wp_t);

  // QK = x @ w_qk^T : [8192][8192] bf16 (cols 0..4095 = Q, 4096..8191 = K)
  gemm_bt<0><<<dim3(64, 64), 256, 0, stream>>>(x_bf, wqk_bf, qk_bf, nullptr, 8192, 8192, 512);
  // V = x @ w_v + b_v, stored transposed [ (b*8+h)*64+d ][ t ]
  gemm_bt<1><<<dim3(64, 4), 256, 0, stream>>>(x_bf, wv_t, v_t, bv, 8192, 512, 512);

  flash_attn<<<512, 256, 0, stream>>>(qk_bf, v_t, ctx_bf);

  // out = ctx @ w_proj + b_proj (f32)
  gemm_bt<2><<<dim3(64, 4), 256, 0, stream>>>(ctx_bf, wp_t, d_out, bp, 8192, 512, 512);
}